// Round 4
// baseline (348.493 us; speedup 1.0000x reference)
//
#include <hip/hip_runtime.h>
#include <hip/hip_bf16.h>
#include <cstdint>

typedef __attribute__((ext_vector_type(8))) short bf16x8;
typedef __attribute__((ext_vector_type(4))) float f32x4;

__device__ inline uint16_t f2bf(float f) {
  uint32_t u = __float_as_uint(f);
  u += 0x7FFF + ((u >> 16) & 1);          // round-to-nearest-even
  return (uint16_t)(u >> 16);
}

// ---------------- prep1: s_feat (RMS-normalized), rgb coefs ----------------
__global__ __launch_bounds__(256) void prep1_kernel(
    const float* __restrict__ w,        // (2,512)
    const float* __restrict__ afw,      // (128,512)
    const float* __restrict__ afb,      // (128)
    const float* __restrict__ argbw,    // (128,512)
    const float* __restrict__ argbb,    // (128)
    const float* __restrict__ wrgb,     // (3,128)
    const float* __restrict__ ema_r,    // (1)
    float* __restrict__ s_feat_out,     // (2,128)
    float* __restrict__ coef_out)       // (2,3,128)
{
  __shared__ float sfeat_s[256];
  __shared__ float srgb_s[256];
  __shared__ float sred[256];
  const int tid = threadIdx.x, lane = tid & 63, wv = tid >> 6;
  const float wg = 0.04419417382415922f;    // 1/sqrt(512)
  #pragma unroll 2
  for (int p = wv; p < 256; p += 4) {
    const int bb = p >> 7, c = p & 127;
    float d1 = 0.f, d2 = 0.f;
    #pragma unroll
    for (int it = 0; it < 8; ++it) {
      const int k = lane + 64*it;
      const float wvv = w[bb*512 + k];
      d1 += wvv * afw[c*512 + k];
      d2 += wvv * argbw[c*512 + k];
    }
    #pragma unroll
    for (int off = 32; off; off >>= 1) {
      d1 += __shfl_xor(d1, off, 64);
      d2 += __shfl_xor(d2, off, 64);
    }
    if (lane == 0) {
      sfeat_s[p] = d1 * wg + afb[c];
      srgb_s[p]  = (d2 * wg + argbb[c]) * 0.08838834764831845f * rsqrtf(ema_r[0]);
    }
  }
  __syncthreads();
  const float sf = sfeat_s[tid];
  sred[tid] = sf * sf;
  __syncthreads();
  for (int off = 128; off > 0; off >>= 1) {
    if (tid < off) sred[tid] += sred[tid + off];
    __syncthreads();
  }
  const float snorm = rsqrtf(sred[0] * (1.0f/256.0f));
  s_feat_out[tid] = sf * snorm;
  for (int e = tid; e < 768; e += 256) {
    int bb = e / 384, o = (e % 384) / 128, i = e & 127;
    coef_out[e] = wrgb[o*128 + i] * srgb_s[bb*128 + i];
  }
}

// ---------------- prep2: wnscale (inline) + modulate + demod -> bf16 A-fragments ----------------
// wfrag layout: [b][kidx 0..35][mglob 0..7][lane 0..63][j 0..7]  (short/bf16)
__global__ __launch_bounds__(128) void prep2_kernel(
    const float* __restrict__ wfeat, const float* __restrict__ s_feat,
    const float* __restrict__ ema_f, short* __restrict__ wfrag)
{
  __shared__ float red[128];
  const int bo = blockIdx.x, b = bo >> 7, o = bo & 127;
  const int i = threadIdx.x;
  float wraw[9]; float ssr = 0.f;
  #pragma unroll
  for (int j = 0; j < 9; ++j) { wraw[j] = wfeat[(o*128 + i)*9 + j]; ssr += wraw[j]*wraw[j]; }
  red[i] = ssr; __syncthreads();
  for (int off = 64; off > 0; off >>= 1) { if (i < off) red[i] += red[i+off]; __syncthreads(); }
  const float wsc = rsqrtf(red[0] * (1.0f/1152.0f));
  const float sv = s_feat[b*128 + i];
  float wr[9]; float ss = 0.f;
  #pragma unroll
  for (int j = 0; j < 9; ++j) { wr[j] = wraw[j] * wsc * sv; ss += wr[j]*wr[j]; }
  __syncthreads();
  red[i] = ss; __syncthreads();
  for (int off = 64; off > 0; off >>= 1) { if (i < off) red[i] += red[i+off]; __syncthreads(); }
  const float d = rsqrtf(red[0] + 1e-8f) * rsqrtf(ema_f[0]);
  const int chunk = i >> 5;
  const int lane = (o & 15) | (((i >> 3) & 3) << 4);
  const int jj = i & 7;
  #pragma unroll
  for (int tap = 0; tap < 9; ++tap) {
    int kidx = chunk*9 + tap;
    size_t sidx = ((((size_t)b*36 + kidx)*8 + (o >> 4)) << 9) + (lane << 3) + jj;
    wfrag[sidx] = (short)f2bf(wr[tap] * d);
  }
}

// ---------------- conv via bf16 MFMA implicit GEMM ----------------
// block: 128 oc x (4 rows x 32 cols); 4 waves 2x2; wave 64 oc x 64 px.
// x staged per 32-ic chunk into LDS [r<6][col<40][icp<16 packed], 2 buffers,
// 2-deep register prefetch (float4-pair loads over aligned 40-col window).
__global__ __launch_bounds__(256, 3) void conv_mfma_kernel(
    const float* __restrict__ x, const short* __restrict__ wfrag,
    const float* __restrict__ bias_feat, float* __restrict__ conv_out)
{
  __shared__ char xs[2][19200];
  __shared__ float bias_lds[128];
  const int tid = threadIdx.x;
  const int bx = blockIdx.x, by = blockIdx.y, b = blockIdx.z;
  const int x0 = bx * 32, y0 = by * 4;
  const int lane = tid & 63, wave = tid >> 6;
  const int wm = wave >> 1, wn = wave & 1;
  const int l15 = lane & 15, lq = lane >> 4;
  if (tid < 128) bias_lds[tid] = bias_feat[tid];

  f32x4 acc[4][4] = {};

  // ---- precompute staging item descriptors: item = (icp<16, r<6, slot<10) ----
  const float* xb = x + (size_t)b * 8388608;   // b*128*65536
  int goff[4]; int lb[4]; bool okv[4];
  #pragma unroll
  for (int i = 0; i < 4; ++i) {
    const int e = tid + 256*i;
    const int slot = e % 10; const int rr = e / 10;
    const int r = rr % 6; const int icp = rr / 6;
    const int gy = y0 - 2 + r;
    const int gx0 = x0 - 4 + 4*slot;
    const bool act = e < 960;
    const bool ok = act && ((unsigned)gy < 256u) && (gx0 >= 0) && (gx0 <= 252);
    okv[i] = ok;
    goff[i] = ok ? ((icp*2)*65536 + gy*256 + gx0) : 0;
    lb[i] = (r*40 + 4*slot)*80 + ((((icp>>2) ^ ((slot>>1)&3) ^ (r&3))) << 4) + ((icp&3) << 2);
  }

  const short* wbase = wfrag + (((size_t)b*36*8) + (size_t)wm*4) * 512 + (size_t)lane * 8;

  float4 r0a[4], r1a[4], r0b[4], r1b[4];   // two register banks (ic even / ic+1)
  const float4 f4z = {0.f, 0.f, 0.f, 0.f};

  auto LOAD = [&](int ch, float4* r0, float4* r1) {
    #pragma unroll
    for (int i = 0; i < 4; ++i) {
      const float* p = xb + goff[i] + (size_t)ch * 2097152;   // ch*32*65536
      r0[i] = okv[i] ? *(const float4*)p : f4z;
      r1[i] = okv[i] ? *(const float4*)(p + 65536) : f4z;
    }
  };
  auto WRITE = [&](int buf, const float4* r0, const float4* r1) {
    char* base = xs[buf];
    #pragma unroll
    for (int i = 0; i < 4; ++i) {
      if (i < 3 || tid < 192) {
        #pragma unroll
        for (int j = 0; j < 4; ++j) {
          uint32_t pk = ((uint32_t)f2bf(r1[i][j]) << 16) | f2bf(r0[i][j]);
          *(uint32_t*)(base + lb[i] + 80*j) = pk;
        }
      }
    }
  };
  auto COMPUTE = [&](int buf, int ch) {
    const char* base = xs[buf];
    #pragma unroll
    for (int ky = 0; ky < 3; ++ky) {
      #pragma unroll
      for (int kx = 0; kx < 3; ++kx) {
        const int kidx = ch*9 + ky*3 + kx;
        const short* wp = wbase + (size_t)kidx * 4096;
        bf16x8 a_[4];
        #pragma unroll
        for (int m = 0; m < 4; ++m) a_[m] = *(const bf16x8*)(wp + m*512);
        bf16x8 bfr[4];
        #pragma unroll
        for (int n = 0; n < 4; ++n) {
          const int r = wn*2 + (n>>1) + ky;
          const int c = (n&1)*16 + l15 + kx + 2;
          bfr[n] = *(const bf16x8*)&base[(r*40 + c)*80 + ((lq ^ ((c>>3)&3) ^ (r&3)) << 4)];
        }
        __builtin_amdgcn_s_setprio(1);
        #pragma unroll
        for (int m = 0; m < 4; ++m)
          #pragma unroll
          for (int n = 0; n < 4; ++n)
            acc[m][n] = __builtin_amdgcn_mfma_f32_16x16x32_bf16(a_[m], bfr[n], acc[m][n], 0, 0, 0);
        __builtin_amdgcn_s_setprio(0);
      }
    }
  };

  // prologue: chunk0 staged, chunk1 loads in flight
  LOAD(0, r0a, r1a);
  WRITE(0, r0a, r1a);
  LOAD(1, r0b, r1b);
  __syncthreads();

  #pragma unroll
  for (int ch = 0; ch < 4; ++ch) {
    if (ch < 2) {                       // 2-deep prefetch into the freed bank
      if ((ch & 1) == 0) LOAD(ch + 2, r0a, r1a);
      else               LOAD(ch + 2, r0b, r1b);
    }
    COMPUTE(ch & 1, ch);
    if (ch < 3) {
      if (((ch + 1) & 1) == 0) WRITE(0, r0a, r1a);
      else                     WRITE(1, r0b, r1b);
      __syncthreads();
    }
  }

  // epilogue: D col = pixel (lane&15), row = oc ((lane>>4)*4 + j)
  #pragma unroll
  for (int n = 0; n < 4; ++n) {
    const int py = y0 + wn*2 + (n>>1);
    const int px = x0 + (n&1)*16 + l15;
    if (py < 258 && px < 258) {
      #pragma unroll
      for (int m = 0; m < 4; ++m) {
        const int oc0 = wm*64 + m*16 + lq*4;
        float* dst = conv_out + ((size_t)(b*128 + oc0)*258 + py)*258 + px;
        #pragma unroll
        for (int j = 0; j < 4; ++j)
          dst[(size_t)j*66564] = acc[m][n][j] + bias_lds[oc0 + j];
      }
    }
  }
}

// ---------------- fused up2x (sep) + lrelu/clamp + down2x (sep) ----------------
__global__ __launch_bounds__(256) void updown_kernel(
    const float* __restrict__ conv_out,
    const float* __restrict__ upf, const float* __restrict__ dnf,
    float* __restrict__ down2)
{
  __shared__ float Bp[26][268];   // up1 strip; cols [4,262) live, 4 zero-pad left, 6 right
  __shared__ float Dp[8][524];    // down1 strip (522 live cols + pad)
  const int strip = blockIdx.x, c = blockIdx.y, b = blockIdx.z;
  const int y0 = strip * 8;
  const int tid = threadIdx.x;
  float fu[12], fd[12];
  #pragma unroll
  for (int k = 0; k < 12; ++k) { fu[k] = upf[11-k] * 2.0f; fd[k] = dnf[11-k]; }
  for (int e = tid; e < 260; e += 256) {
    int r = e / 10, pc = e % 10;
    int col = (pc < 4) ? pc : (258 + pc);
    Bp[r][col] = 0.f;
  }
  const float* src = conv_out + ((size_t)(b*128 + c)*258)*258;

  // P1: vertical upsample, global -> LDS (threads over columns m)
  #pragma unroll 1
  for (int m = tid; m < 258; m += 256) {
    float a[18];
    #pragma unroll
    for (int r = 0; r < 18; ++r) {
      int gy = y0 - 4 + r;
      a[r] = ((unsigned)gy < 258u) ? src[gy*258 + m] : 0.f;
    }
    #pragma unroll
    for (int v = 0; v < 26; ++v) {
      const int k0 = (v & 1) ? 0 : 1;
      float sacc = 0.f;
      #pragma unroll
      for (int j = 0; j < 6; ++j) {
        const int rl = (v + k0 + 2*j - 9)/2 + 4;
        sacc += fu[k0 + 2*j] * a[rl];
      }
      Bp[v][m + 4] = sacc;
    }
  }
  __syncthreads();

  // P2: horizontal upsample + lrelu + vertical downsample (b64 reads + parity select)
  #pragma unroll 1
  for (int q = tid; q < 261; q += 256) {
    const int qa = q & ~1;
    const int h = q & 1;
    float cc0[26], cc1[26];
    #pragma unroll
    for (int v = 0; v < 26; ++v) {
      float f[8];
      #pragma unroll
      for (int t = 0; t < 4; ++t)
        *(float2*)&f[2*t] = *(const float2*)&Bp[v][qa + 2*t];
      float w0 = h ? f[1] : f[0];
      float w1 = h ? f[2] : f[1];
      float w2 = h ? f[3] : f[2];
      float w3 = h ? f[4] : f[3];
      float w4 = h ? f[5] : f[4];
      float w5 = h ? f[6] : f[5];
      float c0 = fu[1]*w0 + fu[3]*w1 + fu[5]*w2 + fu[7]*w3 + fu[9]*w4 + fu[11]*w5;
      float c1 = fu[0]*w0 + fu[2]*w1 + fu[4]*w2 + fu[6]*w3 + fu[8]*w4 + fu[10]*w5;
      cc0[v] = fminf(fmaxf((c0 < 0.f ? c0*0.2f : c0)*1.41421356237f, -256.f), 256.f);
      cc1[v] = fminf(fmaxf((c1 < 0.f ? c1*0.2f : c1)*1.41421356237f, -256.f), 256.f);
    }
    #pragma unroll
    for (int t = 0; t < 8; ++t) {
      float a0 = 0.f, a1 = 0.f;
      #pragma unroll
      for (int k = 0; k < 12; ++k) {
        a0 += fd[k]*cc0[2*t + k];
        a1 += fd[k]*cc1[2*t + k];
      }
      float2 pr; pr.x = a0; pr.y = a1;
      *(float2*)&Dp[t][2*q] = pr;
    }
  }
  __syncthreads();

  // P3: horizontal downsample, LDS -> global; output pairs via 4x ds_read_b128
  const int ty = tid >> 5, xg = tid & 31;
  float* dstrow = down2 + ((size_t)(b*128 + c)*256 + (y0 + ty))*256;
  #pragma unroll
  for (int p = 0; p < 4; ++p) {
    const int pi = xg + 32*p;          // output pair index: outputs 2pi, 2pi+1
    float fx[16];
    #pragma unroll
    for (int t = 0; t < 4; ++t)
      *(float4*)&fx[4*t] = *(const float4*)&Dp[ty][4*pi + 4*t];
    float o0 = 0.f, o1 = 0.f;
    #pragma unroll
    for (int k = 0; k < 12; ++k) {
      o0 += fd[k] * fx[k];
      o1 += fd[k] * fx[k + 2];
    }
    float2 st; st.x = o0; st.y = o1;
    *(float2*)&dstrow[2*pi] = st;
  }
}

// ---------------- rgb ----------------
__global__ __launch_bounds__(256) void rgb_kernel(
    const float* __restrict__ down2, const float* __restrict__ coef,
    const float* __restrict__ brgb, float* __restrict__ yout)
{
  __shared__ float cl[3][128];
  const int b = blockIdx.x >> 8;
  const int p = ((blockIdx.x & 255) << 8) + threadIdx.x;
  for (int e = threadIdx.x; e < 384; e += 256) cl[e >> 7][e & 127] = coef[b*384 + e];
  __syncthreads();
  float a0 = 0.f, a1 = 0.f, a2 = 0.f;
  const float* dsrc = down2 + (size_t)b*128*65536 + p;
  #pragma unroll 4
  for (int i = 0; i < 128; ++i) {
    float v = dsrc[(size_t)i*65536];
    a0 += cl[0][i]*v; a1 += cl[1][i]*v; a2 += cl[2][i]*v;
  }
  const size_t ob = (size_t)b*3*65536 + p;
  yout[ob]          = fminf(fmaxf(a0 + brgb[0], -256.f), 256.f);
  yout[ob + 65536]  = fminf(fmaxf(a1 + brgb[1], -256.f), 256.f);
  yout[ob + 131072] = fminf(fmaxf(a2 + brgb[2], -256.f), 256.f);
}

extern "C" void kernel_launch(void* const* d_in, const int* in_sizes, int n_in,
                              void* d_out, int out_size, void* d_ws, size_t ws_size,
                              hipStream_t stream) {
  const float* x      = (const float*)d_in[0];
  const float* w      = (const float*)d_in[1];
  const float* afw    = (const float*)d_in[2];
  const float* afb    = (const float*)d_in[3];
  const float* wfeat  = (const float*)d_in[4];
  const float* bfeat  = (const float*)d_in[5];
  const float* argbw  = (const float*)d_in[6];
  const float* argbb  = (const float*)d_in[7];
  const float* wrgb   = (const float*)d_in[8];
  const float* brgb   = (const float*)d_in[9];
  const float* upf    = (const float*)d_in[10];
  const float* dnf    = (const float*)d_in[11];
  const float* emaf   = (const float*)d_in[12];
  const float* emar   = (const float*)d_in[13];

  float* ws = (float*)d_ws;
  size_t off = 0;
  float* s_feat   = ws + off; off += 256;
  float* coef     = ws + off; off += 768;
  short* wfrag    = (short*)(ws + off); off += 147456;          // 294912 bf16
  float* conv_out = ws + off; off += (size_t)2*128*258*258;     // 17,040,384
  float* down2    = ws + off; off += (size_t)2*128*256*256;     // 16,777,216
  if (ws_size < off * sizeof(float)) return;
  float* yout = (float*)d_out;

  prep1_kernel<<<1, 256, 0, stream>>>(w, afw, afb, argbw, argbb, wrgb, emar,
                                      s_feat, coef);
  prep2_kernel<<<256, 128, 0, stream>>>(wfeat, s_feat, emaf, wfrag);
  conv_mfma_kernel<<<dim3(9, 65, 2), 256, 0, stream>>>(x, wfrag, bfeat, conv_out);
  updown_kernel<<<dim3(32, 128, 2), 256, 0, stream>>>(conv_out, upf, dnf, down2);
  rgb_kernel<<<512, 256, 0, stream>>>(down2, coef, brgb, yout);
}

// Round 5
// 250.681 us; speedup vs baseline: 1.3902x; 1.3902x over previous
//
#include <hip/hip_runtime.h>
#include <hip/hip_bf16.h>
#include <cstdint>

typedef __attribute__((ext_vector_type(8))) short bf16x8;
typedef __attribute__((ext_vector_type(4))) float f32x4;

__device__ inline uint16_t f2bf(float f) {
  uint32_t u = __float_as_uint(f);
  u += 0x7FFF + ((u >> 16) & 1);          // round-to-nearest-even
  return (uint16_t)(u >> 16);
}

// ---------------- prep1: s_feat (RMS-normalized), rgb coefs ----------------
__global__ __launch_bounds__(256) void prep1_kernel(
    const float* __restrict__ w,        // (2,512)
    const float* __restrict__ afw,      // (128,512)
    const float* __restrict__ afb,      // (128)
    const float* __restrict__ argbw,    // (128,512)
    const float* __restrict__ argbb,    // (128)
    const float* __restrict__ wrgb,     // (3,128)
    const float* __restrict__ ema_r,    // (1)
    float* __restrict__ s_feat_out,     // (2,128)
    float* __restrict__ coef_out)       // (2,3,128)
{
  __shared__ float sfeat_s[256];
  __shared__ float srgb_s[256];
  __shared__ float sred[256];
  const int tid = threadIdx.x, lane = tid & 63, wv = tid >> 6;
  const float wg = 0.04419417382415922f;    // 1/sqrt(512)
  #pragma unroll 2
  for (int p = wv; p < 256; p += 4) {
    const int bb = p >> 7, c = p & 127;
    float d1 = 0.f, d2 = 0.f;
    #pragma unroll
    for (int it = 0; it < 8; ++it) {
      const int k = lane + 64*it;
      const float wvv = w[bb*512 + k];
      d1 += wvv * afw[c*512 + k];
      d2 += wvv * argbw[c*512 + k];
    }
    #pragma unroll
    for (int off = 32; off; off >>= 1) {
      d1 += __shfl_xor(d1, off, 64);
      d2 += __shfl_xor(d2, off, 64);
    }
    if (lane == 0) {
      sfeat_s[p] = d1 * wg + afb[c];
      srgb_s[p]  = (d2 * wg + argbb[c]) * 0.08838834764831845f * rsqrtf(ema_r[0]);
    }
  }
  __syncthreads();
  const float sf = sfeat_s[tid];
  sred[tid] = sf * sf;
  __syncthreads();
  for (int off = 128; off > 0; off >>= 1) {
    if (tid < off) sred[tid] += sred[tid + off];
    __syncthreads();
  }
  const float snorm = rsqrtf(sred[0] * (1.0f/256.0f));
  s_feat_out[tid] = sf * snorm;
  for (int e = tid; e < 768; e += 256) {
    int bb = e / 384, o = (e % 384) / 128, i = e & 127;
    coef_out[e] = wrgb[o*128 + i] * srgb_s[bb*128 + i];
  }
}

// ---------------- prep2: wnscale (inline) + modulate + demod -> bf16 fragments ----------------
// wfrag layout: [b][kidx 0..35][mglob 0..7][lane 0..63][j 0..7]  (short/bf16)
__global__ __launch_bounds__(128) void prep2_kernel(
    const float* __restrict__ wfeat, const float* __restrict__ s_feat,
    const float* __restrict__ ema_f, short* __restrict__ wfrag)
{
  __shared__ float red[128];
  const int bo = blockIdx.x, b = bo >> 7, o = bo & 127;
  const int i = threadIdx.x;
  float wraw[9]; float ssr = 0.f;
  #pragma unroll
  for (int j = 0; j < 9; ++j) { wraw[j] = wfeat[(o*128 + i)*9 + j]; ssr += wraw[j]*wraw[j]; }
  red[i] = ssr; __syncthreads();
  for (int off = 64; off > 0; off >>= 1) { if (i < off) red[i] += red[i+off]; __syncthreads(); }
  const float wsc = rsqrtf(red[0] * (1.0f/1152.0f));
  const float sv = s_feat[b*128 + i];
  float wr[9]; float ss = 0.f;
  #pragma unroll
  for (int j = 0; j < 9; ++j) { wr[j] = wraw[j] * wsc * sv; ss += wr[j]*wr[j]; }
  __syncthreads();
  red[i] = ss; __syncthreads();
  for (int off = 64; off > 0; off >>= 1) { if (i < off) red[i] += red[i+off]; __syncthreads(); }
  const float d = rsqrtf(red[0] + 1e-8f) * rsqrtf(ema_f[0]);
  const int chunk = i >> 5;
  const int lane = (o & 15) | (((i >> 3) & 3) << 4);
  const int jj = i & 7;
  #pragma unroll
  for (int tap = 0; tap < 9; ++tap) {
    int kidx = chunk*9 + tap;
    size_t sidx = ((((size_t)b*36 + kidx)*8 + (o >> 4)) << 9) + (lane << 3) + jj;
    wfrag[sidx] = (short)f2bf(wr[tap] * d);
  }
}

// ---------------- conv via bf16 MFMA implicit GEMM, single full-x stage ----------------
// block: 128 oc x (4 rows x 32 cols) px; 4 waves (wp=px-half, wo=oc-half); wave 64px x 64oc.
// LDS x layout: unit(r,g,c) = 16B (8 ic), addr = ((r*16+g)*42 + c)*16; r<6, g=ic>>3<16, c<40.
// MFMA: A = x (M=px), B = w (N=oc) -> lane stores 4 consecutive px (float4 epilogue).
__global__ __launch_bounds__(256, 2) void conv_mfma_kernel(
    const float* __restrict__ x, const short* __restrict__ wfrag,
    const float* __restrict__ bias_feat, float* __restrict__ conv_out)
{
  __shared__ __align__(16) char xls[64512];
  __shared__ float bias_lds[128];
  const int tid = threadIdx.x;
  const int bx = blockIdx.x, by = blockIdx.y, b = blockIdx.z;
  const int x0 = bx * 32, y0 = by * 4;
  if (tid < 128) bias_lds[tid] = bias_feat[tid];

  const f32x4 f4z = {0.f, 0.f, 0.f, 0.f};
  const float* xb = x + (size_t)b * 8388608;

  // ---- stage whole x tile: 128 ic x 6 r x 40 c (fp32 -> bf16 pairs) ----
  {
    const int slot = tid & 7, pL = tid >> 3;            // pL 0..31
    const int gx0m = x0 - 4 + 4*slot;
    const bool xokm = (unsigned)gx0m <= 252u;
    #pragma unroll
    for (int r = 0; r < 6; ++r) {
      const int gy = y0 - 2 + r;
      const bool yok = (unsigned)gy < 256u;
      #pragma unroll
      for (int ph = 0; ph < 2; ++ph) {
        const int p = pL + 32*ph;                       // ic pair 0..63
        const float* s0 = xb + (size_t)(2*p)*65536 + gy*256 + gx0m;
        const bool ok = yok && xokm;
        f32x4 v0 = ok ? *(const f32x4*)s0 : f4z;
        f32x4 v1 = ok ? *(const f32x4*)(s0 + 65536) : f4z;
        char* wb = xls + (size_t)(((r*16 + (p>>2))*42 + 4*slot)*16 + (p&3)*4);
        #pragma unroll
        for (int i2 = 0; i2 < 4; ++i2) {
          uint32_t pk = ((uint32_t)f2bf(v1[i2]) << 16) | f2bf(v0[i2]);
          *(uint32_t*)(wb + i2*16) = pk;
        }
      }
    }
    // tail: cols 32..39
    #pragma unroll
    for (int k3 = 0; k3 < 3; ++k3) {
      const int e = tid + 256*k3;                       // 0..767
      const int sl = e & 1;
      const int p  = (e >> 1) & 63;
      const int r  = e >> 7;                            // 0..5
      const int gy = y0 - 2 + r;
      const int gxt = x0 + 28 + 4*sl;
      const bool ok = ((unsigned)gy < 256u) && ((unsigned)gxt <= 252u);
      const float* s0 = xb + (size_t)(2*p)*65536 + gy*256 + gxt;
      f32x4 v0 = ok ? *(const f32x4*)s0 : f4z;
      f32x4 v1 = ok ? *(const f32x4*)(s0 + 65536) : f4z;
      char* wb = xls + (size_t)(((r*16 + (p>>2))*42 + 32 + 4*sl)*16 + (p&3)*4);
      #pragma unroll
      for (int i2 = 0; i2 < 4; ++i2) {
        uint32_t pk = ((uint32_t)f2bf(v1[i2]) << 16) | f2bf(v0[i2]);
        *(uint32_t*)(wb + i2*16) = pk;
      }
    }
  }
  __syncthreads();

  // ---- K-loop: 36 kidx, A(x) from LDS, B(w) from global with 2-deep reg prefetch ----
  const int lane = tid & 63, wave = tid >> 6;
  const int wp = wave & 1, wo = wave >> 1;
  const int l15 = lane & 15, lq = lane >> 4;
  const short* wbase = wfrag + ((size_t)b*288 + wo*4)*512 + (size_t)lane*8;
  const int abase = ((wp*32 + lq)*42 + l15 + 2)*16;     // r-base = wp*2 rows -> wp*2*16*42*16

  f32x4 acc[4][4] = {};

  bf16x8 wf0[4], wf1[4];

#define LDW(KI, WF) { const short* wp_ = wbase + (size_t)(KI)*4096;          \
    WF[0] = *(const bf16x8*)(wp_);       WF[1] = *(const bf16x8*)(wp_+512);  \
    WF[2] = *(const bf16x8*)(wp_+1024);  WF[3] = *(const bf16x8*)(wp_+1536); }

#define KSTEP(KI, WF) {                                                       \
    const int ch_ = (KI)/9, tp_ = (KI)%9, ky_ = tp_/3, kx_ = tp_%3;           \
    const int o00 = ((ky_*16 + ch_*4)*42 + kx_)*16;                           \
    const int o10 = (((1+ky_)*16 + ch_*4)*42 + kx_)*16;                       \
    bf16x8 xf0 = *(const bf16x8*)(xls + abase + o00);                         \
    bf16x8 xf1 = *(const bf16x8*)(xls + abase + o00 + 256);                   \
    bf16x8 xf2 = *(const bf16x8*)(xls + abase + o10);                         \
    bf16x8 xf3 = *(const bf16x8*)(xls + abase + o10 + 256);                   \
    __builtin_amdgcn_s_setprio(1);                                            \
    acc[0][0] = __builtin_amdgcn_mfma_f32_16x16x32_bf16(xf0, WF[0], acc[0][0], 0,0,0); \
    acc[0][1] = __builtin_amdgcn_mfma_f32_16x16x32_bf16(xf0, WF[1], acc[0][1], 0,0,0); \
    acc[0][2] = __builtin_amdgcn_mfma_f32_16x16x32_bf16(xf0, WF[2], acc[0][2], 0,0,0); \
    acc[0][3] = __builtin_amdgcn_mfma_f32_16x16x32_bf16(xf0, WF[3], acc[0][3], 0,0,0); \
    acc[1][0] = __builtin_amdgcn_mfma_f32_16x16x32_bf16(xf1, WF[0], acc[1][0], 0,0,0); \
    acc[1][1] = __builtin_amdgcn_mfma_f32_16x16x32_bf16(xf1, WF[1], acc[1][1], 0,0,0); \
    acc[1][2] = __builtin_amdgcn_mfma_f32_16x16x32_bf16(xf1, WF[2], acc[1][2], 0,0,0); \
    acc[1][3] = __builtin_amdgcn_mfma_f32_16x16x32_bf16(xf1, WF[3], acc[1][3], 0,0,0); \
    acc[2][0] = __builtin_amdgcn_mfma_f32_16x16x32_bf16(xf2, WF[0], acc[2][0], 0,0,0); \
    acc[2][1] = __builtin_amdgcn_mfma_f32_16x16x32_bf16(xf2, WF[1], acc[2][1], 0,0,0); \
    acc[2][2] = __builtin_amdgcn_mfma_f32_16x16x32_bf16(xf2, WF[2], acc[2][2], 0,0,0); \
    acc[2][3] = __builtin_amdgcn_mfma_f32_16x16x32_bf16(xf2, WF[3], acc[2][3], 0,0,0); \
    acc[3][0] = __builtin_amdgcn_mfma_f32_16x16x32_bf16(xf3, WF[0], acc[3][0], 0,0,0); \
    acc[3][1] = __builtin_amdgcn_mfma_f32_16x16x32_bf16(xf3, WF[1], acc[3][1], 0,0,0); \
    acc[3][2] = __builtin_amdgcn_mfma_f32_16x16x32_bf16(xf3, WF[2], acc[3][2], 0,0,0); \
    acc[3][3] = __builtin_amdgcn_mfma_f32_16x16x32_bf16(xf3, WF[3], acc[3][3], 0,0,0); \
    __builtin_amdgcn_s_setprio(0); }

  LDW(0, wf0);
  LDW(1, wf1);
  #pragma unroll
  for (int kk = 0; kk < 36; kk += 2) {
    KSTEP(kk, wf0);
    if (kk + 2 < 36) LDW(kk + 2, wf0);
    KSTEP(kk + 1, wf1);
    if (kk + 3 < 36) LDW(kk + 3, wf1);
  }
#undef LDW
#undef KSTEP

  // ---- epilogue: lane holds px = x0+(p&1)*16+lq*4+j (contig), oc = wo*64+o*16+l15 ----
  #pragma unroll
  for (int p = 0; p < 4; ++p) {
    const int py = y0 + wp*2 + (p>>1);
    if (py >= 258) continue;
    const int px0 = x0 + (p&1)*16 + lq*4;
    #pragma unroll
    for (int o = 0; o < 4; ++o) {
      const int oc = wo*64 + o*16 + l15;
      const float bz = bias_lds[oc];
      f32x4 v = acc[p][o];
      v[0] += bz; v[1] += bz; v[2] += bz; v[3] += bz;
      float* dst = conv_out + ((size_t)(b*128 + oc)*258 + py)*258 + px0;
      if (px0 <= 254) {
        *(f32x4*)dst = v;
      } else {
        #pragma unroll
        for (int j = 0; j < 4; ++j)
          if (px0 + j < 258) dst[j] = v[j];
      }
    }
  }
}

// ---------------- fused up2x (sep) + lrelu/clamp + down2x (sep) ----------------
__global__ __launch_bounds__(256) void updown_kernel(
    const float* __restrict__ conv_out,
    const float* __restrict__ upf, const float* __restrict__ dnf,
    float* __restrict__ down2)
{
  __shared__ float Bp[26][268];   // up1 strip; cols [4,262) live, zero-pad sides
  __shared__ float Dp[8][524];    // down1 strip (522 live cols + pad)
  const int strip = blockIdx.x, c = blockIdx.y, b = blockIdx.z;
  const int y0 = strip * 8;
  const int tid = threadIdx.x;
  float fu[12], fd[12];
  #pragma unroll
  for (int k = 0; k < 12; ++k) { fu[k] = upf[11-k] * 2.0f; fd[k] = dnf[11-k]; }
  for (int e = tid; e < 260; e += 256) {
    int r = e / 10, pc = e % 10;
    int col = (pc < 4) ? pc : (258 + pc);
    Bp[r][col] = 0.f;
  }
  const float* src = conv_out + ((size_t)(b*128 + c)*258)*258;

  // P1: vertical upsample, global -> LDS (threads over columns m)
  #pragma unroll 1
  for (int m = tid; m < 258; m += 256) {
    float a[18];
    #pragma unroll
    for (int r = 0; r < 18; ++r) {
      int gy = y0 - 4 + r;
      a[r] = ((unsigned)gy < 258u) ? src[gy*258 + m] : 0.f;
    }
    #pragma unroll
    for (int v = 0; v < 26; ++v) {
      const int k0 = (v & 1) ? 0 : 1;
      float sacc = 0.f;
      #pragma unroll
      for (int j = 0; j < 6; ++j) {
        const int rl = (v + k0 + 2*j - 9)/2 + 4;
        sacc += fu[k0 + 2*j] * a[rl];
      }
      Bp[v][m + 4] = sacc;
    }
  }
  __syncthreads();

  // P2: horizontal upsample + lrelu + vertical downsample
  #pragma unroll 1
  for (int q = tid; q < 261; q += 256) {
    const int qa = q & ~1;
    const int h = q & 1;
    float cc0[26], cc1[26];
    #pragma unroll
    for (int v = 0; v < 26; ++v) {
      float f[8];
      #pragma unroll
      for (int t = 0; t < 4; ++t)
        *(float2*)&f[2*t] = *(const float2*)&Bp[v][qa + 2*t];
      float w0 = h ? f[1] : f[0];
      float w1 = h ? f[2] : f[1];
      float w2 = h ? f[3] : f[2];
      float w3 = h ? f[4] : f[3];
      float w4 = h ? f[5] : f[4];
      float w5 = h ? f[6] : f[5];
      float c0 = fu[1]*w0 + fu[3]*w1 + fu[5]*w2 + fu[7]*w3 + fu[9]*w4 + fu[11]*w5;
      float c1 = fu[0]*w0 + fu[2]*w1 + fu[4]*w2 + fu[6]*w3 + fu[8]*w4 + fu[10]*w5;
      cc0[v] = fminf(fmaxf((c0 < 0.f ? c0*0.2f : c0)*1.41421356237f, -256.f), 256.f);
      cc1[v] = fminf(fmaxf((c1 < 0.f ? c1*0.2f : c1)*1.41421356237f, -256.f), 256.f);
    }
    #pragma unroll
    for (int t = 0; t < 8; ++t) {
      float a0 = 0.f, a1 = 0.f;
      #pragma unroll
      for (int k = 0; k < 12; ++k) {
        a0 += fd[k]*cc0[2*t + k];
        a1 += fd[k]*cc1[2*t + k];
      }
      float2 pr; pr.x = a0; pr.y = a1;
      *(float2*)&Dp[t][2*q] = pr;
    }
  }
  __syncthreads();

  // P3: horizontal downsample, LDS -> global
  const int ty = tid >> 5, xg = tid & 31;
  float* dstrow = down2 + ((size_t)(b*128 + c)*256 + (y0 + ty))*256;
  #pragma unroll
  for (int p = 0; p < 4; ++p) {
    const int pi = xg + 32*p;
    float fx[16];
    #pragma unroll
    for (int t = 0; t < 4; ++t)
      *(float4*)&fx[4*t] = *(const float4*)&Dp[ty][4*pi + 4*t];
    float o0 = 0.f, o1 = 0.f;
    #pragma unroll
    for (int k = 0; k < 12; ++k) {
      o0 += fd[k] * fx[k];
      o1 += fd[k] * fx[k + 2];
    }
    float2 st; st.x = o0; st.y = o1;
    *(float2*)&dstrow[2*pi] = st;
  }
}

// ---------------- rgb: float4 per thread ----------------
__global__ __launch_bounds__(128) void rgb_kernel(
    const float* __restrict__ down2, const float* __restrict__ coef,
    const float* __restrict__ brgb, float* __restrict__ yout)
{
  __shared__ float cl[3][128];
  const int b = blockIdx.x >> 7;
  const int p4 = ((blockIdx.x & 127) << 7) + threadIdx.x;   // float4 idx 0..16383
  for (int e = threadIdx.x; e < 384; e += 128) cl[e >> 7][e & 127] = coef[b*384 + e];
  __syncthreads();
  f32x4 a0 = {0,0,0,0}, a1 = {0,0,0,0}, a2 = {0,0,0,0};
  const f32x4* dsrc = (const f32x4*)down2 + (size_t)b*2097152 + p4;
  #pragma unroll 4
  for (int i = 0; i < 128; ++i) {
    f32x4 v = dsrc[(size_t)i*16384];
    a0 += cl[0][i]*v; a1 += cl[1][i]*v; a2 += cl[2][i]*v;
  }
  f32x4* yo = (f32x4*)yout;
  const float b0 = brgb[0], b1 = brgb[1], b2 = brgb[2];
  #pragma unroll
  for (int j = 0; j < 4; ++j) {
    a0[j] = fminf(fmaxf(a0[j] + b0, -256.f), 256.f);
    a1[j] = fminf(fmaxf(a1[j] + b1, -256.f), 256.f);
    a2[j] = fminf(fmaxf(a2[j] + b2, -256.f), 256.f);
  }
  yo[(size_t)(b*3 + 0)*16384 + p4] = a0;
  yo[(size_t)(b*3 + 1)*16384 + p4] = a1;
  yo[(size_t)(b*3 + 2)*16384 + p4] = a2;
}

extern "C" void kernel_launch(void* const* d_in, const int* in_sizes, int n_in,
                              void* d_out, int out_size, void* d_ws, size_t ws_size,
                              hipStream_t stream) {
  const float* x      = (const float*)d_in[0];
  const float* w      = (const float*)d_in[1];
  const float* afw    = (const float*)d_in[2];
  const float* afb    = (const float*)d_in[3];
  const float* wfeat  = (const float*)d_in[4];
  const float* bfeat  = (const float*)d_in[5];
  const float* argbw  = (const float*)d_in[6];
  const float* argbb  = (const float*)d_in[7];
  const float* wrgb   = (const float*)d_in[8];
  const float* brgb   = (const float*)d_in[9];
  const float* upf    = (const float*)d_in[10];
  const float* dnf    = (const float*)d_in[11];
  const float* emaf   = (const float*)d_in[12];
  const float* emar   = (const float*)d_in[13];

  float* ws = (float*)d_ws;
  size_t off = 0;
  float* s_feat   = ws + off; off += 256;
  float* coef     = ws + off; off += 768;
  short* wfrag    = (short*)(ws + off); off += 147456;          // 294912 bf16
  float* conv_out = ws + off; off += (size_t)2*128*258*258;     // 17,040,384
  float* down2    = ws + off; off += (size_t)2*128*256*256;     // 16,777,216
  if (ws_size < off * sizeof(float)) return;
  float* yout = (float*)d_out;

  prep1_kernel<<<1, 256, 0, stream>>>(w, afw, afb, argbw, argbb, wrgb, emar,
                                      s_feat, coef);
  prep2_kernel<<<256, 128, 0, stream>>>(wfeat, s_feat, emaf, wfrag);
  conv_mfma_kernel<<<dim3(9, 65, 2), 256, 0, stream>>>(x, wfrag, bfeat, conv_out);
  updown_kernel<<<dim3(32, 128, 2), 256, 0, stream>>>(conv_out, upf, dnf, down2);
  rgb_kernel<<<256, 128, 0, stream>>>(down2, coef, brgb, yout);
}